// Round 3
// baseline (247.768 us; speedup 1.0000x reference)
//
#include <hip/hip_runtime.h>

typedef __attribute__((ext_vector_type(8))) short short8;
typedef __attribute__((ext_vector_type(4))) short short4v;
typedef __attribute__((ext_vector_type(4))) float f32x4;

#define MFMA(a, b, c) __builtin_amdgcn_mfma_f32_16x16x32_bf16((a), (b), (c), 0, 0, 0)

static __device__ __forceinline__ float b2f(unsigned short b) {
  union { unsigned u; float f; } u; u.u = ((unsigned)b) << 16; return u.f;
}
static __device__ __forceinline__ unsigned short f2b(float f) {
  union { float f; unsigned u; } u; u.f = f;
  unsigned r = u.u + 0x7FFFu + ((u.u >> 16) & 1u);
  return (unsigned short)(r >> 16);
}

// C[M x 1024] = A[M x 1024] * W^T, W fp32 [N x K] row-major.
// A fp32 (A_BF16=false) or bf16 (A_BF16=true). C bf16 (OUT_F32=false) or fp32.
// 128x128 tile, BK=32, 4 waves in 2x2, each wave 4x4 16x16 fragments.
template <bool A_BF16, bool OUT_F32>
__global__ __launch_bounds__(256) void gemm_bt(
    const void* __restrict__ Av,
    const float* __restrict__ W0,
    const float* __restrict__ W1,
    const float* __restrict__ W2,
    void* __restrict__ C0v,
    void* __restrict__ C1v,
    void* __restrict__ C2v) {
  const int Kd = 1024, Nd = 1024;
  const float* W = (blockIdx.z == 0) ? W0 : (blockIdx.z == 1) ? W1 : W2;
  void* Cv = (blockIdx.z == 0) ? C0v : (blockIdx.z == 1) ? C1v : C2v;
  __shared__ unsigned short As[128][40];  // +8 pad: 2-way bank alias only (free)
  __shared__ unsigned short Bs[128][40];
  const int tid = threadIdx.x, wave = tid >> 6, lane = tid & 63;
  const int bm = blockIdx.x << 7, bn = blockIdx.y << 7;
  const int wr = (wave >> 1) << 6, wc = (wave & 1) << 6;
  const int lr = lane & 15, lk8 = (lane >> 4) << 3;
  f32x4 acc[4][4] = {};
  for (int k0 = 0; k0 < Kd; k0 += 32) {
    __syncthreads();
    // stage W: 128 rows x 32 fp32 -> bf16
#pragma unroll
    for (int it = 0; it < 4; ++it) {
      int t = tid + (it << 8);
      int row = t >> 3, c4 = (t & 7) << 2;
      float4 v = *(const float4*)&W[(size_t)(bn + row) * Kd + k0 + c4];
      short4v s;
      s[0] = (short)f2b(v.x); s[1] = (short)f2b(v.y);
      s[2] = (short)f2b(v.z); s[3] = (short)f2b(v.w);
      *(short4v*)&Bs[row][c4] = s;
    }
    if constexpr (A_BF16) {
      const unsigned short* A = (const unsigned short*)Av;
#pragma unroll
      for (int it = 0; it < 2; ++it) {
        int t = tid + (it << 8);
        int row = t >> 2, col = (t & 3) << 3;
        *(short8*)&As[row][col] = *(const short8*)&A[(size_t)(bm + row) * Kd + k0 + col];
      }
    } else {
      const float* A = (const float*)Av;
#pragma unroll
      for (int it = 0; it < 4; ++it) {
        int t = tid + (it << 8);
        int row = t >> 3, c4 = (t & 7) << 2;
        float4 v = *(const float4*)&A[(size_t)(bm + row) * Kd + k0 + c4];
        short4v s;
        s[0] = (short)f2b(v.x); s[1] = (short)f2b(v.y);
        s[2] = (short)f2b(v.z); s[3] = (short)f2b(v.w);
        *(short4v*)&As[row][c4] = s;
      }
    }
    __syncthreads();
    short8 af[4], bfr[4];
#pragma unroll
    for (int x = 0; x < 4; ++x) {
      af[x]  = *(const short8*)&As[wr + x * 16 + lr][lk8];
      bfr[x] = *(const short8*)&Bs[wc + x * 16 + lr][lk8];
    }
#pragma unroll
    for (int mm = 0; mm < 4; ++mm)
#pragma unroll
      for (int nn = 0; nn < 4; ++nn)
        acc[mm][nn] = MFMA(af[mm], bfr[nn], acc[mm][nn]);
  }
  const int rg = (lane >> 4) << 2;
#pragma unroll
  for (int mm = 0; mm < 4; ++mm)
#pragma unroll
    for (int nn = 0; nn < 4; ++nn)
#pragma unroll
      for (int r = 0; r < 4; ++r) {
        size_t idx = (size_t)(bm + wr + mm * 16 + rg + r) * Nd + (bn + wc + nn * 16 + lr);
        if constexpr (OUT_F32)
          ((float*)Cv)[idx] = acc[mm][nn][r];
        else
          ((unsigned short*)Cv)[idx] = f2b(acc[mm][nn][r]);
      }
}

// RoPE in-place on bf16 Q and K; folds attention scale 0.125 into Q (exact in bf16).
// cos/sin fp32 [T][1][64], halves duplicated -> use low 32 for both halves.
__global__ __launch_bounds__(256) void rope_kernel(
    unsigned short* __restrict__ Q, unsigned short* __restrict__ K,
    const float* __restrict__ cosb, const float* __restrict__ sinb) {
  int i = blockIdx.x * 256 + threadIdx.x;  // T*H*4 threads
  int g = i & 3, h = (i >> 2) & 15, t = i >> 6;
  size_t base = (size_t)t * 1024 + h * 64 + (g << 3);
  int cb = t * 64 + (g << 3);
  short8 ql = *(short8*)&Q[base], qh = *(short8*)&Q[base + 32];
  short8 kl = *(short8*)&K[base], kh = *(short8*)&K[base + 32];
  float c[8], s[8];
  *(float4*)&c[0] = *(const float4*)&cosb[cb];
  *(float4*)&c[4] = *(const float4*)&cosb[cb + 4];
  *(float4*)&s[0] = *(const float4*)&sinb[cb];
  *(float4*)&s[4] = *(const float4*)&sinb[cb + 4];
  short8 oql, oqh, okl, okh;
#pragma unroll
  for (int j = 0; j < 8; ++j) {
    float xl = b2f((unsigned short)ql[j]), xh = b2f((unsigned short)qh[j]);
    oql[j] = (short)f2b((xl * c[j] - xh * s[j]) * 0.125f);
    oqh[j] = (short)f2b((xh * c[j] + xl * s[j]) * 0.125f);
    xl = b2f((unsigned short)kl[j]); xh = b2f((unsigned short)kh[j]);
    okl[j] = (short)f2b(xl * c[j] - xh * s[j]);
    okh[j] = (short)f2b(xh * c[j] + xl * s[j]);
  }
  *(short8*)&Q[base] = oql; *(short8*)&Q[base + 32] = oqh;
  *(short8*)&K[base] = okl; *(short8*)&K[base + 32] = okh;
}

// Causal flash attention. grid (B*H=128, S/64=16), 256 threads (4 waves x 16 q-rows).
// Q pre-scaled by 0.125. K row-major in LDS; V transposed in LDS; P via per-wave LDS.
__global__ __launch_bounds__(256) void attn_kernel(
    const unsigned short* __restrict__ Q,
    const unsigned short* __restrict__ K,
    const unsigned short* __restrict__ V,
    unsigned short* __restrict__ O) {
  __shared__ unsigned short Ks[64][72];      // [key][d], +8 pad
  __shared__ unsigned short Vt[64][72];      // [d][key]
  __shared__ unsigned short Ps[4][16][72];   // per-wave P transpose buffer
  const int tid = threadIdx.x, wave = tid >> 6, lane = tid & 63;
  const int bh = blockIdx.x, b = bh >> 4, h = bh & 15;
  const int qb = blockIdx.y;
  const int tok0 = b << 10;
  const int lr = lane & 15, lk8 = (lane >> 4) << 3;
  const int qrow0 = (qb << 6) + (wave << 4);

  short8 qf0, qf1;
  {
    const unsigned short* qp = &Q[(size_t)(tok0 + qrow0 + lr) * 1024 + h * 64];
    qf0 = *(const short8*)&qp[lk8];
    qf1 = *(const short8*)&qp[32 + lk8];
  }
  f32x4 acc[4] = {};
  float m[4], l[4];
#pragma unroll
  for (int r = 0; r < 4; ++r) { m[r] = -1e30f; l[r] = 0.f; }

  const int nkb = qb + 1;
  for (int kb = 0; kb < nkb; ++kb) {
    __syncthreads();
#pragma unroll
    for (int it = 0; it < 2; ++it) {
      int t = tid + (it << 8);
      int row = t >> 3, col = (t & 7) << 3;
      size_t gidx = (size_t)(tok0 + (kb << 6) + row) * 1024 + h * 64 + col;
      *(short8*)&Ks[row][col] = *(const short8*)&K[gidx];
      short8 vv = *(const short8*)&V[gidx];
#pragma unroll
      for (int j = 0; j < 8; ++j) Vt[col + j][row] = (unsigned short)vv[j];
    }
    __syncthreads();

    float sc[4][4];  // [col-tile][reg]
#pragma unroll
    for (int ct = 0; ct < 4; ++ct) {
      short8 kf0 = *(const short8*)&Ks[ct * 16 + lr][lk8];
      short8 kf1 = *(const short8*)&Ks[ct * 16 + lr][32 + lk8];
      f32x4 s = {};
      s = MFMA(qf0, kf0, s);
      s = MFMA(qf1, kf1, s);
#pragma unroll
      for (int r = 0; r < 4; ++r) sc[ct][r] = s[r];
    }
    if (kb == qb) {  // diagonal block: mask key > q
#pragma unroll
      for (int ct = 0; ct < 4; ++ct)
#pragma unroll
        for (int r = 0; r < 4; ++r) {
          int q_l = (wave << 4) + ((lane >> 4) << 2) + r;
          int k_l = ct * 16 + lr;
          if (k_l > q_l) sc[ct][r] = -1e30f;
        }
    }
    float mt[4];
#pragma unroll
    for (int r = 0; r < 4; ++r)
      mt[r] = fmaxf(fmaxf(sc[0][r], sc[1][r]), fmaxf(sc[2][r], sc[3][r]));
#pragma unroll
    for (int off = 1; off < 16; off <<= 1)
#pragma unroll
      for (int r = 0; r < 4; ++r) mt[r] = fmaxf(mt[r], __shfl_xor(mt[r], off));
    float alpha[4], rs[4];
#pragma unroll
    for (int r = 0; r < 4; ++r) {
      float mn = fmaxf(m[r], mt[r]);
      alpha[r] = __expf(m[r] - mn);
      m[r] = mn;
      rs[r] = 0.f;
    }
    float p[4][4];
#pragma unroll
    for (int ct = 0; ct < 4; ++ct)
#pragma unroll
      for (int r = 0; r < 4; ++r) {
        p[ct][r] = __expf(sc[ct][r] - m[r]);
        rs[r] += p[ct][r];
      }
#pragma unroll
    for (int off = 1; off < 16; off <<= 1)
#pragma unroll
      for (int r = 0; r < 4; ++r) rs[r] += __shfl_xor(rs[r], off);
#pragma unroll
    for (int r = 0; r < 4; ++r) l[r] = l[r] * alpha[r] + rs[r];
#pragma unroll
    for (int dt = 0; dt < 4; ++dt)
#pragma unroll
      for (int r = 0; r < 4; ++r) acc[dt][r] *= alpha[r];
    // transpose P through per-wave LDS (no cross-wave barrier needed)
#pragma unroll
    for (int ct = 0; ct < 4; ++ct)
#pragma unroll
      for (int r = 0; r < 4; ++r)
        Ps[wave][((lane >> 4) << 2) + r][ct * 16 + lr] = f2b(p[ct][r]);
    asm volatile("s_waitcnt lgkmcnt(0)" ::: "memory");
    __builtin_amdgcn_sched_barrier(0);
#pragma unroll
    for (int kk = 0; kk < 2; ++kk) {
      short8 pf = *(const short8*)&Ps[wave][lr][kk * 32 + lk8];
#pragma unroll
      for (int dt = 0; dt < 4; ++dt) {
        short8 vf = *(const short8*)&Vt[dt * 16 + lr][kk * 32 + lk8];
        acc[dt] = MFMA(pf, vf, acc[dt]);
      }
    }
  }
  const int rg = (lane >> 4) << 2;
#pragma unroll
  for (int dt = 0; dt < 4; ++dt)
#pragma unroll
    for (int r = 0; r < 4; ++r) {
      int trow = tok0 + qrow0 + rg + r;
      O[(size_t)trow * 1024 + h * 64 + dt * 16 + lr] = f2b(acc[dt][r] / l[r]);
    }
}

extern "C" void kernel_launch(void* const* d_in, const int* in_sizes, int n_in,
                              void* d_out, int out_size, void* d_ws, size_t ws_size,
                              hipStream_t stream) {
  const float* hidden = (const float*)d_in[0];
  const float* q_w    = (const float*)d_in[1];
  const float* k_w    = (const float*)d_in[2];
  const float* v_w    = (const float*)d_in[3];
  const float* o_w    = (const float*)d_in[4];
  const float* cosb   = (const float*)d_in[5];
  const float* sinb   = (const float*)d_in[6];

  const size_t TD = (size_t)8192 * 1024;
  unsigned short* ws = (unsigned short*)d_ws;
  unsigned short* Qb = ws;
  unsigned short* Kb = ws + TD;
  unsigned short* Vb = ws + 2 * TD;
  unsigned short* AO = ws + 3 * TD;

  dim3 g_qkv(64, 8, 3);
  gemm_bt<false, false><<<g_qkv, 256, 0, stream>>>(hidden, q_w, k_w, v_w, Qb, Kb, Vb);
  rope_kernel<<<2048, 256, 0, stream>>>(Qb, Kb, cosb, sinb);
  dim3 g_attn(128, 16);
  attn_kernel<<<g_attn, 256, 0, stream>>>(Qb, Kb, Vb, AO);
  dim3 g_o(64, 8, 1);
  gemm_bt<true, true><<<g_o, 256, 0, stream>>>(AO, o_w, o_w, o_w, d_out, d_out, d_out);
}

// Round 4
// 200.245 us; speedup vs baseline: 1.2373x; 1.2373x over previous
//
#include <hip/hip_runtime.h>

typedef __attribute__((ext_vector_type(8))) short short8;
typedef __attribute__((ext_vector_type(4))) short short4v;
typedef __attribute__((ext_vector_type(4))) float f32x4;

#define MFMA(a, b, c) __builtin_amdgcn_mfma_f32_16x16x32_bf16((a), (b), (c), 0, 0, 0)

static __device__ __forceinline__ float b2f(unsigned short b) {
  union { unsigned u; float f; } u; u.u = ((unsigned)b) << 16; return u.f;
}
static __device__ __forceinline__ unsigned short f2b(float f) {
  union { float f; unsigned u; } u; u.f = f;
  unsigned r = u.u + 0x7FFFu + ((u.u >> 16) & 1u);
  return (unsigned short)(r >> 16);
}

// fp32 -> bf16 convert. Layout (float4 units):
// [hidden 2097152][q_w 262144][k_w][v_w][o_w], dst = contiguous shorts.
__global__ __launch_bounds__(256) void convert_kernel(
    const float* __restrict__ hidden,
    const float* __restrict__ qw, const float* __restrict__ kw,
    const float* __restrict__ vw, const float* __restrict__ ow,
    unsigned short* __restrict__ dst) {
  const int HID4 = 2097152, W4 = 262144, TOT = HID4 + 4 * W4;
  for (int i = blockIdx.x * 256 + threadIdx.x; i < TOT; i += gridDim.x * 256) {
    const float* src; int off;
    if (i < HID4) { src = hidden; off = i; }
    else {
      int j = i - HID4; int w = j >> 18; off = j & (W4 - 1);
      src = (w == 0) ? qw : (w == 1) ? kw : (w == 2) ? vw : ow;
    }
    float4 v = *(const float4*)&src[(size_t)off * 4];
    short4v s;
    s[0] = (short)f2b(v.x); s[1] = (short)f2b(v.y);
    s[2] = (short)f2b(v.z); s[3] = (short)f2b(v.w);
    *(short4v*)&dst[(size_t)i * 4] = s;
  }
}

// C[8192 x N] = A[8192 x 1024](bf16) * W^T (W [N x 1024] bf16 row-major).
// m97 structure: 128x128 tile, BK=64, global_load_lds 16B with XOR-swizzled
// source + swizzled ds_read_b128 (conflict-free). 4 waves 2x2, 4x4 frags.
// QKV=true: N=3072, writes bf16 Q/K/V (TD apart), RoPE fused for groups 0,1
// (group 0 also scaled 0.125). QKV=false: N=1024, writes fp32 to Cv.
template <bool QKV>
__global__ __launch_bounds__(256) void gemm_bf16(
    const unsigned short* __restrict__ A,
    const unsigned short* __restrict__ W,
    void* __restrict__ Cv,
    const float* __restrict__ cosb, const float* __restrict__ sinb) {
  __shared__ __align__(16) char raw[32768];
  unsigned short* As = (unsigned short*)raw;   // [128][64] swizzled
  unsigned short* Bs = As + 8192;
  const int tid = threadIdx.x, wave = tid >> 6, lane = tid & 63;
  const int bm = blockIdx.x << 7, bnc = blockIdx.y << 7;
  const int wr = (wave >> 1) << 6, wc = (wave & 1) << 6;
  const int lr = lane & 15, hi4 = lane >> 4;
  f32x4 acc[4][4] = {};
  for (int k0 = 0; k0 < 1024; k0 += 64) {
    __syncthreads();
#pragma unroll
    for (int i = 0; i < 4; ++i) {
      int s = (i << 8) + tid;
      int row = s >> 3, cg = (s & 7) ^ (row & 7);  // pre-swizzled global col-group
      const unsigned short* ga = &A[(size_t)(bm + row) * 1024 + k0 + (cg << 3)];
      const unsigned short* gb = &W[(size_t)(bnc + row) * 1024 + k0 + (cg << 3)];
      __builtin_amdgcn_global_load_lds(
          (const __attribute__((address_space(1))) void*)ga,
          (__attribute__((address_space(3))) void*)(As + s * 8), 16, 0, 0);
      __builtin_amdgcn_global_load_lds(
          (const __attribute__((address_space(1))) void*)gb,
          (__attribute__((address_space(3))) void*)(Bs + s * 8), 16, 0, 0);
    }
    __syncthreads();  // drains vmcnt(0) before barrier
    short8 af[2][4], bfr[2][4];
#pragma unroll
    for (int kk = 0; kk < 2; ++kk)
#pragma unroll
      for (int x = 0; x < 4; ++x) {
        int ra = wr + x * 16 + lr;
        af[kk][x] = *(const short8*)&As[ra * 64 + (((hi4 + kk * 4) ^ (ra & 7)) << 3)];
        int rb = wc + x * 16 + lr;
        bfr[kk][x] = *(const short8*)&Bs[rb * 64 + (((hi4 + kk * 4) ^ (rb & 7)) << 3)];
      }
#pragma unroll
    for (int kk = 0; kk < 2; ++kk)
#pragma unroll
      for (int mm = 0; mm < 4; ++mm)
#pragma unroll
        for (int nn = 0; nn < 4; ++nn)
          acc[mm][nn] = MFMA(af[kk][mm], bfr[kk][nn], acc[mm][nn]);
  }
  const int rg = hi4 << 2;
  if constexpr (QKV) {
    const int grp = bnc >> 10;  // 0=Q 1=K 2=V
    unsigned short* Cbuf = (unsigned short*)Cv + (size_t)grp * 8388608;
    const int colbase = (bnc & 1023) + wc;
    if (grp < 2) {
      __syncthreads();  // all MFMAs done reading LDS; reuse for cos/sin (fp32)
      float* csf = (float*)raw;      // [128][32]
      float* snf = csf + 4096;
#pragma unroll
      for (int i = 0; i < 4; ++i) {
        int s = tid * 4 + i;              // 1024 slots = 128 rows x 8 float4
        int row = s >> 3, g = (s & 7) << 2;
        *(float4*)&csf[row * 32 + g] = *(const float4*)&cosb[(size_t)(bm + row) * 64 + g];
        *(float4*)&snf[row * 32 + g] = *(const float4*)&sinb[(size_t)(bm + row) * 64 + g];
      }
      __syncthreads();
      const float sc = (grp == 0) ? 0.125f : 1.0f;
#pragma unroll
      for (int mm = 0; mm < 4; ++mm)
#pragma unroll
        for (int r = 0; r < 4; ++r) {
          int rloc = wr + mm * 16 + rg + r;
          size_t rowoff = (size_t)(bm + rloc) * 1024;
#pragma unroll
          for (int nn = 0; nn < 2; ++nn) {
            int d = nn * 16 + lr;  // 0..31; partner col is d+32 (acc[mm][nn+2])
            float c = csf[rloc * 32 + d], s2 = snf[rloc * 32 + d];
            float lo = acc[mm][nn][r], hi = acc[mm][nn + 2][r];
            Cbuf[rowoff + colbase + nn * 16 + lr]      = f2b((lo * c - hi * s2) * sc);
            Cbuf[rowoff + colbase + nn * 16 + lr + 32] = f2b((hi * c + lo * s2) * sc);
          }
        }
    } else {
#pragma unroll
      for (int mm = 0; mm < 4; ++mm)
#pragma unroll
        for (int nn = 0; nn < 4; ++nn)
#pragma unroll
          for (int r = 0; r < 4; ++r)
            Cbuf[(size_t)(bm + wr + mm * 16 + rg + r) * 1024 + colbase + nn * 16 + lr] =
                f2b(acc[mm][nn][r]);
    }
  } else {
    float* C = (float*)Cv;
#pragma unroll
    for (int mm = 0; mm < 4; ++mm)
#pragma unroll
      for (int nn = 0; nn < 4; ++nn)
#pragma unroll
        for (int r = 0; r < 4; ++r)
          C[(size_t)(bm + wr + mm * 16 + rg + r) * 1024 + bnc + wc + nn * 16 + lr] =
              acc[mm][nn][r];
  }
}

// Causal flash attention (unchanged from round 3). grid (128, 16), 256 thr.
__global__ __launch_bounds__(256) void attn_kernel(
    const unsigned short* __restrict__ Q,
    const unsigned short* __restrict__ K,
    const unsigned short* __restrict__ V,
    unsigned short* __restrict__ O) {
  __shared__ unsigned short Ks[64][72];
  __shared__ unsigned short Vt[64][72];
  __shared__ unsigned short Ps[4][16][72];
  const int tid = threadIdx.x, wave = tid >> 6, lane = tid & 63;
  const int bh = blockIdx.x, b = bh >> 4, h = bh & 15;
  const int qb = blockIdx.y;
  const int tok0 = b << 10;
  const int lr = lane & 15, lk8 = (lane >> 4) << 3;
  const int qrow0 = (qb << 6) + (wave << 4);

  short8 qf0, qf1;
  {
    const unsigned short* qp = &Q[(size_t)(tok0 + qrow0 + lr) * 1024 + h * 64];
    qf0 = *(const short8*)&qp[lk8];
    qf1 = *(const short8*)&qp[32 + lk8];
  }
  f32x4 acc[4] = {};
  float m[4], l[4];
#pragma unroll
  for (int r = 0; r < 4; ++r) { m[r] = -1e30f; l[r] = 0.f; }

  const int nkb = qb + 1;
  for (int kb = 0; kb < nkb; ++kb) {
    __syncthreads();
#pragma unroll
    for (int it = 0; it < 2; ++it) {
      int t = tid + (it << 8);
      int row = t >> 3, col = (t & 7) << 3;
      size_t gidx = (size_t)(tok0 + (kb << 6) + row) * 1024 + h * 64 + col;
      *(short8*)&Ks[row][col] = *(const short8*)&K[gidx];
      short8 vv = *(const short8*)&V[gidx];
#pragma unroll
      for (int j = 0; j < 8; ++j) Vt[col + j][row] = (unsigned short)vv[j];
    }
    __syncthreads();

    float sc[4][4];
#pragma unroll
    for (int ct = 0; ct < 4; ++ct) {
      short8 kf0 = *(const short8*)&Ks[ct * 16 + lr][lk8];
      short8 kf1 = *(const short8*)&Ks[ct * 16 + lr][32 + lk8];
      f32x4 s = {};
      s = MFMA(qf0, kf0, s);
      s = MFMA(qf1, kf1, s);
#pragma unroll
      for (int r = 0; r < 4; ++r) sc[ct][r] = s[r];
    }
    if (kb == qb) {
#pragma unroll
      for (int ct = 0; ct < 4; ++ct)
#pragma unroll
        for (int r = 0; r < 4; ++r) {
          int q_l = (wave << 4) + ((lane >> 4) << 2) + r;
          int k_l = ct * 16 + lr;
          if (k_l > q_l) sc[ct][r] = -1e30f;
        }
    }
    float mt[4];
#pragma unroll
    for (int r = 0; r < 4; ++r)
      mt[r] = fmaxf(fmaxf(sc[0][r], sc[1][r]), fmaxf(sc[2][r], sc[3][r]));
#pragma unroll
    for (int off = 1; off < 16; off <<= 1)
#pragma unroll
      for (int r = 0; r < 4; ++r) mt[r] = fmaxf(mt[r], __shfl_xor(mt[r], off));
    float alpha[4], rs[4];
#pragma unroll
    for (int r = 0; r < 4; ++r) {
      float mn = fmaxf(m[r], mt[r]);
      alpha[r] = __expf(m[r] - mn);
      m[r] = mn;
      rs[r] = 0.f;
    }
    float p[4][4];
#pragma unroll
    for (int ct = 0; ct < 4; ++ct)
#pragma unroll
      for (int r = 0; r < 4; ++r) {
        p[ct][r] = __expf(sc[ct][r] - m[r]);
        rs[r] += p[ct][r];
      }
#pragma unroll
    for (int off = 1; off < 16; off <<= 1)
#pragma unroll
      for (int r = 0; r < 4; ++r) rs[r] += __shfl_xor(rs[r], off);
#pragma unroll
    for (int r = 0; r < 4; ++r) l[r] = l[r] * alpha[r] + rs[r];
#pragma unroll
    for (int dt = 0; dt < 4; ++dt)
#pragma unroll
      for (int r = 0; r < 4; ++r) acc[dt][r] *= alpha[r];
#pragma unroll
    for (int ct = 0; ct < 4; ++ct)
#pragma unroll
      for (int r = 0; r < 4; ++r)
        Ps[wave][((lane >> 4) << 2) + r][ct * 16 + lr] = f2b(p[ct][r]);
    asm volatile("s_waitcnt lgkmcnt(0)" ::: "memory");
    __builtin_amdgcn_sched_barrier(0);
#pragma unroll
    for (int kk = 0; kk < 2; ++kk) {
      short8 pf = *(const short8*)&Ps[wave][lr][kk * 32 + lk8];
#pragma unroll
      for (int dt = 0; dt < 4; ++dt) {
        short8 vf = *(const short8*)&Vt[dt * 16 + lr][kk * 32 + lk8];
        acc[dt] = MFMA(pf, vf, acc[dt]);
      }
    }
  }
  const int rg = (lane >> 4) << 2;
#pragma unroll
  for (int dt = 0; dt < 4; ++dt)
#pragma unroll
    for (int r = 0; r < 4; ++r) {
      int trow = tok0 + qrow0 + rg + r;
      O[(size_t)trow * 1024 + h * 64 + dt * 16 + lr] = f2b(acc[dt][r] / l[r]);
    }
}

extern "C" void kernel_launch(void* const* d_in, const int* in_sizes, int n_in,
                              void* d_out, int out_size, void* d_ws, size_t ws_size,
                              hipStream_t stream) {
  const float* hidden = (const float*)d_in[0];
  const float* q_w    = (const float*)d_in[1];
  const float* k_w    = (const float*)d_in[2];
  const float* v_w    = (const float*)d_in[3];
  const float* o_w    = (const float*)d_in[4];
  const float* cosb   = (const float*)d_in[5];
  const float* sinb   = (const float*)d_in[6];

  const size_t TD = (size_t)8192 * 1024;
  unsigned short* ws  = (unsigned short*)d_ws;
  unsigned short* Qb  = ws;
  unsigned short* Kb  = ws + TD;
  unsigned short* Vb  = ws + 2 * TD;
  unsigned short* hBF = ws + 3 * TD;        // hidden bf16; aliased as AO after QKV
  unsigned short* wBF = ws + 4 * TD;        // q,k,v,o weights bf16 (4 x 1M)

  convert_kernel<<<4096, 256, 0, stream>>>(hidden, q_w, k_w, v_w, o_w, hBF);
  gemm_bf16<true><<<dim3(64, 24), 256, 0, stream>>>(hBF, wBF, Qb, cosb, sinb);
  attn_kernel<<<dim3(128, 16), 256, 0, stream>>>(Qb, Kb, Vb, hBF /*AO*/);
  gemm_bf16<false><<<dim3(64, 8), 256, 0, stream>>>(
      hBF, wBF + 3 * 1048576, d_out, nullptr, nullptr);
}

// Round 5
// 184.129 us; speedup vs baseline: 1.3456x; 1.0875x over previous
//
#include <hip/hip_runtime.h>

typedef __attribute__((ext_vector_type(8))) short short8;
typedef __attribute__((ext_vector_type(4))) short short4v;
typedef __attribute__((ext_vector_type(4))) float f32x4;

#define MFMA(a, b, c) __builtin_amdgcn_mfma_f32_16x16x32_bf16((a), (b), (c), 0, 0, 0)

static __device__ __forceinline__ float b2f(unsigned short b) {
  union { unsigned u; float f; } u; u.u = ((unsigned)b) << 16; return u.f;
}
static __device__ __forceinline__ unsigned short f2b(float f) {
  union { float f; unsigned u; } u; u.f = f;
  unsigned r = u.u + 0x7FFFu + ((u.u >> 16) & 1u);
  return (unsigned short)(r >> 16);
}

// fp32 -> bf16 convert. Layout (float4 units):
// [hidden 2097152][q_w 262144][k_w][v_w][o_w], dst = contiguous shorts.
__global__ __launch_bounds__(256) void convert_kernel(
    const float* __restrict__ hidden,
    const float* __restrict__ qw, const float* __restrict__ kw,
    const float* __restrict__ vw, const float* __restrict__ ow,
    unsigned short* __restrict__ dst) {
  const int HID4 = 2097152, W4 = 262144, TOT = HID4 + 4 * W4;
  for (int i = blockIdx.x * 256 + threadIdx.x; i < TOT; i += gridDim.x * 256) {
    const float* src; int off;
    if (i < HID4) { src = hidden; off = i; }
    else {
      int j = i - HID4; int w = j >> 18; off = j & (W4 - 1);
      src = (w == 0) ? qw : (w == 1) ? kw : (w == 2) ? vw : ow;
    }
    float4 v = *(const float4*)&src[(size_t)off * 4];
    short4v s;
    s[0] = (short)f2b(v.x); s[1] = (short)f2b(v.y);
    s[2] = (short)f2b(v.z); s[3] = (short)f2b(v.w);
    *(short4v*)&dst[(size_t)i * 4] = s;
  }
}

// C[8192 x N] = A[8192 x 1024](bf16) * W^T (W [N x 1024] bf16 row-major).
// m97 structure: 128x128 tile, BK=64, global_load_lds 16B with XOR-swizzled
// source + swizzled ds_read_b128. QKV=true: N=3072, RoPE fused. Else fp32 out.
template <bool QKV>
__global__ __launch_bounds__(256) void gemm_bf16(
    const unsigned short* __restrict__ A,
    const unsigned short* __restrict__ W,
    void* __restrict__ Cv,
    const float* __restrict__ cosb, const float* __restrict__ sinb) {
  __shared__ __align__(16) char raw[32768];
  unsigned short* As = (unsigned short*)raw;   // [128][64] swizzled
  unsigned short* Bs = As + 8192;
  const int tid = threadIdx.x, wave = tid >> 6, lane = tid & 63;
  const int bm = blockIdx.x << 7, bnc = blockIdx.y << 7;
  const int wr = (wave >> 1) << 6, wc = (wave & 1) << 6;
  const int lr = lane & 15, hi4 = lane >> 4;
  f32x4 acc[4][4] = {};
  for (int k0 = 0; k0 < 1024; k0 += 64) {
    __syncthreads();
#pragma unroll
    for (int i = 0; i < 4; ++i) {
      int s = (i << 8) + tid;
      int row = s >> 3, cg = (s & 7) ^ (row & 7);
      const unsigned short* ga = &A[(size_t)(bm + row) * 1024 + k0 + (cg << 3)];
      const unsigned short* gb = &W[(size_t)(bnc + row) * 1024 + k0 + (cg << 3)];
      __builtin_amdgcn_global_load_lds(
          (const __attribute__((address_space(1))) void*)ga,
          (__attribute__((address_space(3))) void*)(As + s * 8), 16, 0, 0);
      __builtin_amdgcn_global_load_lds(
          (const __attribute__((address_space(1))) void*)gb,
          (__attribute__((address_space(3))) void*)(Bs + s * 8), 16, 0, 0);
    }
    __syncthreads();
    short8 af[2][4], bfr[2][4];
#pragma unroll
    for (int kk = 0; kk < 2; ++kk)
#pragma unroll
      for (int x = 0; x < 4; ++x) {
        int ra = wr + x * 16 + lr;
        af[kk][x] = *(const short8*)&As[ra * 64 + (((hi4 + kk * 4) ^ (ra & 7)) << 3)];
        int rb = wc + x * 16 + lr;
        bfr[kk][x] = *(const short8*)&Bs[rb * 64 + (((hi4 + kk * 4) ^ (rb & 7)) << 3)];
      }
#pragma unroll
    for (int kk = 0; kk < 2; ++kk)
#pragma unroll
      for (int mm = 0; mm < 4; ++mm)
#pragma unroll
        for (int nn = 0; nn < 4; ++nn)
          acc[mm][nn] = MFMA(af[kk][mm], bfr[kk][nn], acc[mm][nn]);
  }
  const int rg = hi4 << 2;
  if constexpr (QKV) {
    const int grp = bnc >> 10;  // 0=Q 1=K 2=V
    unsigned short* Cbuf = (unsigned short*)Cv + (size_t)grp * 8388608;
    const int colbase = (bnc & 1023) + wc;
    if (grp < 2) {
      __syncthreads();
      float* csf = (float*)raw;      // [128][32]
      float* snf = csf + 4096;
#pragma unroll
      for (int i = 0; i < 4; ++i) {
        int s = tid * 4 + i;
        int row = s >> 3, g = (s & 7) << 2;
        *(float4*)&csf[row * 32 + g] = *(const float4*)&cosb[(size_t)(bm + row) * 64 + g];
        *(float4*)&snf[row * 32 + g] = *(const float4*)&sinb[(size_t)(bm + row) * 64 + g];
      }
      __syncthreads();
      const float sc = (grp == 0) ? 0.125f : 1.0f;
#pragma unroll
      for (int mm = 0; mm < 4; ++mm)
#pragma unroll
        for (int r = 0; r < 4; ++r) {
          int rloc = wr + mm * 16 + rg + r;
          size_t rowoff = (size_t)(bm + rloc) * 1024;
#pragma unroll
          for (int nn = 0; nn < 2; ++nn) {
            int d = nn * 16 + lr;
            float c = csf[rloc * 32 + d], s2 = snf[rloc * 32 + d];
            float lo = acc[mm][nn][r], hi = acc[mm][nn + 2][r];
            Cbuf[rowoff + colbase + nn * 16 + lr]      = f2b((lo * c - hi * s2) * sc);
            Cbuf[rowoff + colbase + nn * 16 + lr + 32] = f2b((hi * c + lo * s2) * sc);
          }
        }
    } else {
#pragma unroll
      for (int mm = 0; mm < 4; ++mm)
#pragma unroll
        for (int nn = 0; nn < 4; ++nn)
#pragma unroll
          for (int r = 0; r < 4; ++r)
            Cbuf[(size_t)(bm + wr + mm * 16 + rg + r) * 1024 + colbase + nn * 16 + lr] =
                f2b(acc[mm][nn][r]);
    }
  } else {
    float* C = (float*)Cv;
#pragma unroll
    for (int mm = 0; mm < 4; ++mm)
#pragma unroll
      for (int nn = 0; nn < 4; ++nn)
#pragma unroll
        for (int r = 0; r < 4; ++r)
          C[(size_t)(bm + wr + mm * 16 + rg + r) * 1024 + bnc + wc + nn * 16 + lr] =
              acc[mm][nn][r];
  }
}

// Causal flash attention v2. grid (B*H=128, S/128=8), 256 thr (4 waves x 32 q-rows).
// Double-buffered K/V (T14 async split, 1 barrier/iter). V staged d-major:
// coalesced ushort loads -> b128 LDS writes (conflict-free). Q pre-scaled 0.125.
__global__ __launch_bounds__(256, 2) void attn_kernel(
    const unsigned short* __restrict__ Q,
    const unsigned short* __restrict__ K,
    const unsigned short* __restrict__ V,
    unsigned short* __restrict__ O) {
  __shared__ unsigned short Ks[2][64][72];   // [buf][key][d]
  __shared__ unsigned short Vt[2][64][72];   // [buf][d][key]
  __shared__ unsigned short Ps[4][16][72];   // per-wave P
  const int tid = threadIdx.x, wave = tid >> 6, lane = tid & 63;
  const int b = blockIdx.x >> 4, h = blockIdx.x & 15;
  const int qb = blockIdx.y;
  const int tok0 = b << 10;
  const int lr = lane & 15, hi4 = lane >> 4, lk8 = hi4 << 3;
  const int rg = hi4 << 2;
  const int qrow0 = (qb << 7) + (wave << 5);  // wave's 32 rows

  short8 qf[2][2];
#pragma unroll
  for (int mt = 0; mt < 2; ++mt) {
    const unsigned short* qp = &Q[(size_t)(tok0 + qrow0 + mt * 16 + lr) * 1024 + h * 64];
#pragma unroll
    for (int kk = 0; kk < 2; ++kk) qf[mt][kk] = *(const short8*)&qp[kk * 32 + lk8];
  }

  f32x4 acc[2][4] = {};
  float m[2][4], l[2][4];
#pragma unroll
  for (int mt = 0; mt < 2; ++mt)
#pragma unroll
    for (int r = 0; r < 4; ++r) { m[mt][r] = -1e30f; l[mt][r] = 0.f; }

  // staging geometry
  const int krow = tid >> 3, kcol = (tid & 7) << 3;  // K: rows krow, krow+32
  const int vd = tid & 63, vko0 = tid >> 6;          // V: d-major, octets vko0, vko0+4
  short8 kst[2], vst[2];

#define LOADT(kbx)                                                                 \
  do {                                                                             \
    const int kr0_ = tok0 + ((kbx) << 6);                                          \
    _Pragma("unroll") for (int it = 0; it < 2; ++it)                               \
        kst[it] = *(const short8*)&K[(size_t)(kr0_ + krow + it * 32) * 1024 +      \
                                     h * 64 + kcol];                               \
    _Pragma("unroll") for (int it = 0; it < 2; ++it) {                             \
      const unsigned short* vp_ =                                                  \
          &V[(size_t)(kr0_ + ((vko0 + it * 4) << 3)) * 1024 + h * 64 + vd];        \
      _Pragma("unroll") for (int i = 0; i < 8; ++i)                                \
          vst[it][i] = (short)vp_[(size_t)i * 1024];                               \
    }                                                                              \
  } while (0)

#define STORET(bi)                                                                 \
  do {                                                                             \
    _Pragma("unroll") for (int it = 0; it < 2; ++it)                               \
        *(short8*)&Ks[bi][krow + it * 32][kcol] = kst[it];                         \
    _Pragma("unroll") for (int it = 0; it < 2; ++it)                               \
        *(short8*)&Vt[bi][vd][(vko0 + it * 4) << 3] = vst[it];                     \
  } while (0)

  const int nkb = (qb + 1) << 1;
  LOADT(0);
  STORET(0);
  __syncthreads();

  for (int kb = 0; kb < nkb; ++kb) {
    const int cur = kb & 1;
    const bool more = (kb + 1 < nkb);
    if (more) LOADT(kb + 1);  // async: in flight during compute (T14)

    // QK^T for both m-tiles, K-fragments read once
    float sc[2][4][4];
#pragma unroll
    for (int ct = 0; ct < 4; ++ct) {
      short8 kf0 = *(const short8*)&Ks[cur][ct * 16 + lr][lk8];
      short8 kf1 = *(const short8*)&Ks[cur][ct * 16 + lr][32 + lk8];
#pragma unroll
      for (int mt = 0; mt < 2; ++mt) {
        f32x4 s = {};
        s = MFMA(qf[mt][0], kf0, s);
        s = MFMA(qf[mt][1], kf1, s);
#pragma unroll
        for (int r = 0; r < 4; ++r) sc[mt][ct][r] = s[r];
      }
    }
    if (kb >= 2 * qb) {  // diagonal region: mask key > q
#pragma unroll
      for (int mt = 0; mt < 2; ++mt)
#pragma unroll
        for (int ct = 0; ct < 4; ++ct)
#pragma unroll
          for (int r = 0; r < 4; ++r) {
            int kg = (kb << 6) + ct * 16 + lr;
            int qg = qrow0 + mt * 16 + rg + r;
            if (kg > qg) sc[mt][ct][r] = -1e30f;
          }
    }

#pragma unroll
    for (int mt = 0; mt < 2; ++mt) {
      float mx[4];
#pragma unroll
      for (int r = 0; r < 4; ++r)
        mx[r] = fmaxf(fmaxf(sc[mt][0][r], sc[mt][1][r]),
                      fmaxf(sc[mt][2][r], sc[mt][3][r]));
#pragma unroll
      for (int off = 1; off < 16; off <<= 1)
#pragma unroll
        for (int r = 0; r < 4; ++r) mx[r] = fmaxf(mx[r], __shfl_xor(mx[r], off));
      float alpha[4], rs[4];
#pragma unroll
      for (int r = 0; r < 4; ++r) {
        float mn = fmaxf(m[mt][r], mx[r]);
        alpha[r] = __expf(m[mt][r] - mn);
        m[mt][r] = mn;
        rs[r] = 0.f;
      }
      float p[4][4];
#pragma unroll
      for (int ct = 0; ct < 4; ++ct)
#pragma unroll
        for (int r = 0; r < 4; ++r) {
          p[ct][r] = __expf(sc[mt][ct][r] - m[mt][r]);
          rs[r] += p[ct][r];
        }
#pragma unroll
      for (int off = 1; off < 16; off <<= 1)
#pragma unroll
        for (int r = 0; r < 4; ++r) rs[r] += __shfl_xor(rs[r], off);
#pragma unroll
      for (int r = 0; r < 4; ++r) l[mt][r] = l[mt][r] * alpha[r] + rs[r];
#pragma unroll
      for (int dt = 0; dt < 4; ++dt)
#pragma unroll
        for (int r = 0; r < 4; ++r) acc[mt][dt][r] *= alpha[r];
#pragma unroll
      for (int ct = 0; ct < 4; ++ct)
#pragma unroll
        for (int r = 0; r < 4; ++r)
          Ps[wave][rg + r][ct * 16 + lr] = f2b(p[ct][r]);
      asm volatile("s_waitcnt lgkmcnt(0)" ::: "memory");
      __builtin_amdgcn_sched_barrier(0);
#pragma unroll
      for (int kk = 0; kk < 2; ++kk) {
        short8 pf = *(const short8*)&Ps[wave][lr][kk * 32 + lk8];
#pragma unroll
        for (int dt = 0; dt < 4; ++dt) {
          short8 vf = *(const short8*)&Vt[cur][dt * 16 + lr][kk * 32 + lk8];
          acc[mt][dt] = MFMA(pf, vf, acc[mt][dt]);
        }
      }
    }

    if (more) {
      STORET(cur ^ 1);   // waits vmcnt via data dep — latency already hidden
      __syncthreads();
    }
  }
#undef LOADT
#undef STORET

#pragma unroll
  for (int mt = 0; mt < 2; ++mt) {
    float inv[4];
#pragma unroll
    for (int r = 0; r < 4; ++r) inv[r] = 1.0f / l[mt][r];
#pragma unroll
    for (int dt = 0; dt < 4; ++dt)
#pragma unroll
      for (int r = 0; r < 4; ++r) {
        int trow = tok0 + qrow0 + mt * 16 + rg + r;
        O[(size_t)trow * 1024 + h * 64 + dt * 16 + lr] = f2b(acc[mt][dt][r] * inv[r]);
      }
  }
}

extern "C" void kernel_launch(void* const* d_in, const int* in_sizes, int n_in,
                              void* d_out, int out_size, void* d_ws, size_t ws_size,
                              hipStream_t stream) {
  const float* hidden = (const float*)d_in[0];
  const float* q_w    = (const float*)d_in[1];
  const float* k_w    = (const float*)d_in[2];
  const float* v_w    = (const float*)d_in[3];
  const float* o_w    = (const float*)d_in[4];
  const float* cosb   = (const float*)d_in[5];
  const float* sinb   = (const float*)d_in[6];

  const size_t TD = (size_t)8192 * 1024;
  unsigned short* ws  = (unsigned short*)d_ws;
  unsigned short* Qb  = ws;
  unsigned short* Kb  = ws + TD;
  unsigned short* Vb  = ws + 2 * TD;
  unsigned short* hBF = ws + 3 * TD;        // hidden bf16; aliased as AO after QKV
  unsigned short* wBF = ws + 4 * TD;        // q,k,v,o weights bf16 (4 x 1M)

  convert_kernel<<<4096, 256, 0, stream>>>(hidden, q_w, k_w, v_w, o_w, hBF);
  gemm_bf16<true><<<dim3(64, 24), 256, 0, stream>>>(hBF, wBF, Qb, cosb, sinb);
  attn_kernel<<<dim3(128, 8), 256, 0, stream>>>(Qb, Kb, Vb, hBF /*AO*/);
  gemm_bf16<false><<<dim3(64, 8), 256, 0, stream>>>(
      hBF, wBF + 3 * 1048576, d_out, nullptr, nullptr);
}

// Round 6
// 166.664 us; speedup vs baseline: 1.4866x; 1.1048x over previous
//
#include <hip/hip_runtime.h>

typedef __attribute__((ext_vector_type(8))) short short8;
typedef __attribute__((ext_vector_type(4))) short short4v;
typedef __attribute__((ext_vector_type(4))) float f32x4;

#define MFMA(a, b, c) __builtin_amdgcn_mfma_f32_16x16x32_bf16((a), (b), (c), 0, 0, 0)

static __device__ __forceinline__ float b2f(unsigned short b) {
  union { unsigned u; float f; } u; u.u = ((unsigned)b) << 16; return u.f;
}
static __device__ __forceinline__ unsigned short f2b(float f) {
  union { float f; unsigned u; } u; u.f = f;
  unsigned r = u.u + 0x7FFFu + ((u.u >> 16) & 1u);
  return (unsigned short)(r >> 16);
}

// fp32 -> bf16 convert. Layout (float4 units):
// [hidden 2097152][q_w 262144][k_w][v_w][o_w], dst = contiguous shorts.
__global__ __launch_bounds__(256) void convert_kernel(
    const float* __restrict__ hidden,
    const float* __restrict__ qw, const float* __restrict__ kw,
    const float* __restrict__ vw, const float* __restrict__ ow,
    unsigned short* __restrict__ dst) {
  const int HID4 = 2097152, W4 = 262144, TOT = HID4 + 4 * W4;
  for (int i = blockIdx.x * 256 + threadIdx.x; i < TOT; i += gridDim.x * 256) {
    const float* src; int off;
    if (i < HID4) { src = hidden; off = i; }
    else {
      int j = i - HID4; int w = j >> 18; off = j & (W4 - 1);
      src = (w == 0) ? qw : (w == 1) ? kw : (w == 2) ? vw : ow;
    }
    float4 v = *(const float4*)&src[(size_t)off * 4];
    short4v s;
    s[0] = (short)f2b(v.x); s[1] = (short)f2b(v.y);
    s[2] = (short)f2b(v.z); s[3] = (short)f2b(v.w);
    *(short4v*)&dst[(size_t)i * 4] = s;
  }
}

// C[8192 x N] = A[8192 x 1024](bf16) * W^T (W [N x 1024] bf16 row-major).
// m97 structure: 128x128 tile, BK=64, global_load_lds 16B with XOR-swizzled
// source + swizzled ds_read_b128. QKV=true: N=3072, RoPE fused. Else fp32 out.
template <bool QKV>
__global__ __launch_bounds__(256) void gemm_bf16(
    const unsigned short* __restrict__ A,
    const unsigned short* __restrict__ W,
    void* __restrict__ Cv,
    const float* __restrict__ cosb, const float* __restrict__ sinb) {
  __shared__ __align__(16) char raw[32768];
  unsigned short* As = (unsigned short*)raw;   // [128][64] swizzled
  unsigned short* Bs = As + 8192;
  const int tid = threadIdx.x, wave = tid >> 6, lane = tid & 63;
  const int bm = blockIdx.x << 7, bnc = blockIdx.y << 7;
  const int wr = (wave >> 1) << 6, wc = (wave & 1) << 6;
  const int lr = lane & 15, hi4 = lane >> 4;
  f32x4 acc[4][4] = {};
  for (int k0 = 0; k0 < 1024; k0 += 64) {
    __syncthreads();
#pragma unroll
    for (int i = 0; i < 4; ++i) {
      int s = (i << 8) + tid;
      int row = s >> 3, cg = (s & 7) ^ (row & 7);
      const unsigned short* ga = &A[(size_t)(bm + row) * 1024 + k0 + (cg << 3)];
      const unsigned short* gb = &W[(size_t)(bnc + row) * 1024 + k0 + (cg << 3)];
      __builtin_amdgcn_global_load_lds(
          (const __attribute__((address_space(1))) void*)ga,
          (__attribute__((address_space(3))) void*)(As + s * 8), 16, 0, 0);
      __builtin_amdgcn_global_load_lds(
          (const __attribute__((address_space(1))) void*)gb,
          (__attribute__((address_space(3))) void*)(Bs + s * 8), 16, 0, 0);
    }
    __syncthreads();
    short8 af[2][4], bfr[2][4];
#pragma unroll
    for (int kk = 0; kk < 2; ++kk)
#pragma unroll
      for (int x = 0; x < 4; ++x) {
        int ra = wr + x * 16 + lr;
        af[kk][x] = *(const short8*)&As[ra * 64 + (((hi4 + kk * 4) ^ (ra & 7)) << 3)];
        int rb = wc + x * 16 + lr;
        bfr[kk][x] = *(const short8*)&Bs[rb * 64 + (((hi4 + kk * 4) ^ (rb & 7)) << 3)];
      }
#pragma unroll
    for (int kk = 0; kk < 2; ++kk)
#pragma unroll
      for (int mm = 0; mm < 4; ++mm)
#pragma unroll
        for (int nn = 0; nn < 4; ++nn)
          acc[mm][nn] = MFMA(af[kk][mm], bfr[kk][nn], acc[mm][nn]);
  }
  const int rg = hi4 << 2;
  if constexpr (QKV) {
    const int grp = bnc >> 10;  // 0=Q 1=K 2=V
    unsigned short* Cbuf = (unsigned short*)Cv + (size_t)grp * 8388608;
    const int colbase = (bnc & 1023) + wc;
    if (grp < 2) {
      __syncthreads();
      float* csf = (float*)raw;      // [128][32]
      float* snf = csf + 4096;
#pragma unroll
      for (int i = 0; i < 4; ++i) {
        int s = tid * 4 + i;
        int row = s >> 3, g = (s & 7) << 2;
        *(float4*)&csf[row * 32 + g] = *(const float4*)&cosb[(size_t)(bm + row) * 64 + g];
        *(float4*)&snf[row * 32 + g] = *(const float4*)&sinb[(size_t)(bm + row) * 64 + g];
      }
      __syncthreads();
      // Q gets 0.125 * log2(e) so attention softmax runs in exp2 domain.
      const float sc = (grp == 0) ? 0.18033688011112042f : 1.0f;
#pragma unroll
      for (int mm = 0; mm < 4; ++mm)
#pragma unroll
        for (int r = 0; r < 4; ++r) {
          int rloc = wr + mm * 16 + rg + r;
          size_t rowoff = (size_t)(bm + rloc) * 1024;
#pragma unroll
          for (int nn = 0; nn < 2; ++nn) {
            int d = nn * 16 + lr;
            float c = csf[rloc * 32 + d], s2 = snf[rloc * 32 + d];
            float lo = acc[mm][nn][r], hi = acc[mm][nn + 2][r];
            Cbuf[rowoff + colbase + nn * 16 + lr]      = f2b((lo * c - hi * s2) * sc);
            Cbuf[rowoff + colbase + nn * 16 + lr + 32] = f2b((hi * c + lo * s2) * sc);
          }
        }
    } else {
#pragma unroll
      for (int mm = 0; mm < 4; ++mm)
#pragma unroll
        for (int nn = 0; nn < 4; ++nn)
#pragma unroll
          for (int r = 0; r < 4; ++r)
            Cbuf[(size_t)(bm + wr + mm * 16 + rg + r) * 1024 + colbase + nn * 16 + lr] =
                f2b(acc[mm][nn][r]);
    }
  } else {
    float* C = (float*)Cv;
#pragma unroll
    for (int mm = 0; mm < 4; ++mm)
#pragma unroll
      for (int nn = 0; nn < 4; ++nn)
#pragma unroll
        for (int r = 0; r < 4; ++r)
          C[(size_t)(bm + wr + mm * 16 + rg + r) * 1024 + bnc + wc + nn * 16 + lr] =
              acc[mm][nn][r];
  }
}

// Causal flash attention v3. 1D grid 1024, heavy q-blocks first (LPT).
// 256 thr (4 waves x 32 q-rows). Double-buffered K/V, d-major V staging,
// defer-max (THR=8, log2 domain), exp2 softmax (log2e folded into Q).
__global__ __launch_bounds__(256, 2) void attn_kernel(
    const unsigned short* __restrict__ Q,
    const unsigned short* __restrict__ K,
    const unsigned short* __restrict__ V,
    unsigned short* __restrict__ O) {
  __shared__ unsigned short Ks[2][64][72];   // [buf][key][d]
  __shared__ unsigned short Vt[2][64][72];   // [buf][d][key]
  __shared__ unsigned short Ps[4][16][72];   // per-wave P
  const int tid = threadIdx.x, wave = tid >> 6, lane = tid & 63;
  const int idx = blockIdx.x;
  const int bh = idx & 127;
  const int b = bh >> 4, h = bh & 15;
  const int qb = 7 - (idx >> 7);             // heavy-first
  const int tok0 = b << 10;
  const int lr = lane & 15, hi4 = lane >> 4, lk8 = hi4 << 3;
  const int rg = hi4 << 2;
  const int qrow0 = (qb << 7) + (wave << 5);

  short8 qf[2][2];
#pragma unroll
  for (int mt = 0; mt < 2; ++mt) {
    const unsigned short* qp = &Q[(size_t)(tok0 + qrow0 + mt * 16 + lr) * 1024 + h * 64];
#pragma unroll
    for (int kk = 0; kk < 2; ++kk) qf[mt][kk] = *(const short8*)&qp[kk * 32 + lk8];
  }

  f32x4 acc[2][4] = {};
  float m[2][4], l[2][4];
#pragma unroll
  for (int mt = 0; mt < 2; ++mt)
#pragma unroll
    for (int r = 0; r < 4; ++r) { m[mt][r] = -1e30f; l[mt][r] = 0.f; }

  const int krow = tid >> 3, kcol = (tid & 7) << 3;
  const int vd = tid & 63, vko0 = tid >> 6;
  short8 kst[2], vst[2];

#define LOADT(kbx)                                                                 \
  do {                                                                             \
    const int kr0_ = tok0 + ((kbx) << 6);                                          \
    _Pragma("unroll") for (int it = 0; it < 2; ++it)                               \
        kst[it] = *(const short8*)&K[(size_t)(kr0_ + krow + it * 32) * 1024 +      \
                                     h * 64 + kcol];                               \
    _Pragma("unroll") for (int it = 0; it < 2; ++it) {                             \
      const unsigned short* vp_ =                                                  \
          &V[(size_t)(kr0_ + ((vko0 + it * 4) << 3)) * 1024 + h * 64 + vd];        \
      _Pragma("unroll") for (int i = 0; i < 8; ++i)                                \
          vst[it][i] = (short)vp_[(size_t)i * 1024];                               \
    }                                                                              \
  } while (0)

#define STORET(bi)                                                                 \
  do {                                                                             \
    _Pragma("unroll") for (int it = 0; it < 2; ++it)                               \
        *(short8*)&Ks[bi][krow + it * 32][kcol] = kst[it];                         \
    _Pragma("unroll") for (int it = 0; it < 2; ++it)                               \
        *(short8*)&Vt[bi][vd][(vko0 + it * 4) << 3] = vst[it];                     \
  } while (0)

  const int nkb = (qb + 1) << 1;
  LOADT(0);
  STORET(0);
  __syncthreads();

  for (int kb = 0; kb < nkb; ++kb) {
    const int cur = kb & 1;
    const bool more = (kb + 1 < nkb);
    if (more) LOADT(kb + 1);

    float sc[2][4][4];
#pragma unroll
    for (int ct = 0; ct < 4; ++ct) {
      short8 kf0 = *(const short8*)&Ks[cur][ct * 16 + lr][lk8];
      short8 kf1 = *(const short8*)&Ks[cur][ct * 16 + lr][32 + lk8];
#pragma unroll
      for (int mt = 0; mt < 2; ++mt) {
        f32x4 s = {};
        s = MFMA(qf[mt][0], kf0, s);
        s = MFMA(qf[mt][1], kf1, s);
#pragma unroll
        for (int r = 0; r < 4; ++r) sc[mt][ct][r] = s[r];
      }
    }
    if (kb >= 2 * qb) {
#pragma unroll
      for (int mt = 0; mt < 2; ++mt)
#pragma unroll
        for (int ct = 0; ct < 4; ++ct)
#pragma unroll
          for (int r = 0; r < 4; ++r) {
            int kg = (kb << 6) + ct * 16 + lr;
            int qg = qrow0 + mt * 16 + rg + r;
            if (kg > qg) sc[mt][ct][r] = -1e30f;
          }
    }

#pragma unroll
    for (int mt = 0; mt < 2; ++mt) {
      float mx[4];
#pragma unroll
      for (int r = 0; r < 4; ++r)
        mx[r] = fmaxf(fmaxf(sc[mt][0][r], sc[mt][1][r]),
                      fmaxf(sc[mt][2][r], sc[mt][3][r]));
#pragma unroll
      for (int off = 1; off < 16; off <<= 1)
#pragma unroll
        for (int r = 0; r < 4; ++r) mx[r] = fmaxf(mx[r], __shfl_xor(mx[r], off));
      // defer-max: rescale only if some row max grew by > 8 (log2 units)
      bool need = (mx[0] > m[mt][0] + 8.f) | (mx[1] > m[mt][1] + 8.f) |
                  (mx[2] > m[mt][2] + 8.f) | (mx[3] > m[mt][3] + 8.f);
      if (__any(need)) {
#pragma unroll
        for (int r = 0; r < 4; ++r) {
          float mn = fmaxf(m[mt][r], mx[r]);
          float alpha = __builtin_amdgcn_exp2f(m[mt][r] - mn);
          m[mt][r] = mn;
          l[mt][r] *= alpha;
#pragma unroll
          for (int dt = 0; dt < 4; ++dt) acc[mt][dt][r] *= alpha;
        }
      }
      float rs[4] = {0.f, 0.f, 0.f, 0.f};
      float p[4][4];
#pragma unroll
      for (int ct = 0; ct < 4; ++ct)
#pragma unroll
        for (int r = 0; r < 4; ++r) {
          p[ct][r] = __builtin_amdgcn_exp2f(sc[mt][ct][r] - m[mt][r]);
          rs[r] += p[ct][r];
        }
#pragma unroll
      for (int off = 1; off < 16; off <<= 1)
#pragma unroll
        for (int r = 0; r < 4; ++r) rs[r] += __shfl_xor(rs[r], off);
#pragma unroll
      for (int r = 0; r < 4; ++r) l[mt][r] += rs[r];
#pragma unroll
      for (int ct = 0; ct < 4; ++ct)
#pragma unroll
        for (int r = 0; r < 4; ++r)
          Ps[wave][rg + r][ct * 16 + lr] = f2b(p[ct][r]);
      asm volatile("s_waitcnt lgkmcnt(0)" ::: "memory");
      __builtin_amdgcn_sched_barrier(0);
#pragma unroll
      for (int kk = 0; kk < 2; ++kk) {
        short8 pf = *(const short8*)&Ps[wave][lr][kk * 32 + lk8];
#pragma unroll
        for (int dt = 0; dt < 4; ++dt) {
          short8 vf = *(const short8*)&Vt[cur][dt * 16 + lr][kk * 32 + lk8];
          acc[mt][dt] = MFMA(pf, vf, acc[mt][dt]);
        }
      }
    }

    if (more) {
      STORET(cur ^ 1);
      __syncthreads();
    }
  }
#undef LOADT
#undef STORET

#pragma unroll
  for (int mt = 0; mt < 2; ++mt) {
    float inv[4];
#pragma unroll
    for (int r = 0; r < 4; ++r) inv[r] = 1.0f / l[mt][r];
#pragma unroll
    for (int dt = 0; dt < 4; ++dt)
#pragma unroll
      for (int r = 0; r < 4; ++r) {
        int trow = tok0 + qrow0 + mt * 16 + rg + r;
        O[(size_t)trow * 1024 + h * 64 + dt * 16 + lr] = f2b(acc[mt][dt][r] * inv[r]);
      }
  }
}

extern "C" void kernel_launch(void* const* d_in, const int* in_sizes, int n_in,
                              void* d_out, int out_size, void* d_ws, size_t ws_size,
                              hipStream_t stream) {
  const float* hidden = (const float*)d_in[0];
  const float* q_w    = (const float*)d_in[1];
  const float* k_w    = (const float*)d_in[2];
  const float* v_w    = (const float*)d_in[3];
  const float* o_w    = (const float*)d_in[4];
  const float* cosb   = (const float*)d_in[5];
  const float* sinb   = (const float*)d_in[6];

  const size_t TD = (size_t)8192 * 1024;
  unsigned short* ws  = (unsigned short*)d_ws;
  unsigned short* Qb  = ws;
  unsigned short* Kb  = ws + TD;
  unsigned short* Vb  = ws + 2 * TD;
  unsigned short* hBF = ws + 3 * TD;        // hidden bf16; aliased as AO after QKV
  unsigned short* wBF = ws + 4 * TD;        // q,k,v,o weights bf16 (4 x 1M)

  convert_kernel<<<4096, 256, 0, stream>>>(hidden, q_w, k_w, v_w, o_w, hBF);
  gemm_bf16<true><<<dim3(64, 24), 256, 0, stream>>>(hBF, wBF, Qb, cosb, sinb);
  attn_kernel<<<1024, 256, 0, stream>>>(Qb, Kb, Vb, hBF /*AO*/);
  gemm_bf16<false><<<dim3(64, 8), 256, 0, stream>>>(
      hBF, wBF + 3 * 1048576, d_out, nullptr, nullptr);
}

// Round 7
// 157.776 us; speedup vs baseline: 1.5704x; 1.0563x over previous
//
#include <hip/hip_runtime.h>

typedef __attribute__((ext_vector_type(8))) short short8;
typedef __attribute__((ext_vector_type(4))) short short4v;
typedef __attribute__((ext_vector_type(4))) float f32x4;

#define MFMA(a, b, c) __builtin_amdgcn_mfma_f32_16x16x32_bf16((a), (b), (c), 0, 0, 0)
#define GLD16(g, l)                                                            \
  __builtin_amdgcn_global_load_lds(                                            \
      (const __attribute__((address_space(1))) void*)(g),                      \
      (__attribute__((address_space(3))) void*)(l), 16, 0, 0)

static __device__ __forceinline__ float b2f(unsigned short b) {
  union { unsigned u; float f; } u; u.u = ((unsigned)b) << 16; return u.f;
}
static __device__ __forceinline__ unsigned short f2b(float f) {
  union { float f; unsigned u; } u; u.f = f;
  unsigned r = u.u + 0x7FFFu + ((u.u >> 16) & 1u);
  return (unsigned short)(r >> 16);
}

// fp32 -> bf16 convert: [hidden][q_w][k_w][v_w][o_w] -> contiguous bf16.
__global__ __launch_bounds__(256) void convert_kernel(
    const float* __restrict__ hidden,
    const float* __restrict__ qw, const float* __restrict__ kw,
    const float* __restrict__ vw, const float* __restrict__ ow,
    unsigned short* __restrict__ dst) {
  const int HID4 = 2097152, W4 = 262144, TOT = HID4 + 4 * W4;
  for (int i = blockIdx.x * 256 + threadIdx.x; i < TOT; i += gridDim.x * 256) {
    const float* src; int off;
    if (i < HID4) { src = hidden; off = i; }
    else {
      int j = i - HID4; int w = j >> 18; off = j & (W4 - 1);
      src = (w == 0) ? qw : (w == 1) ? kw : (w == 2) ? vw : ow;
    }
    float4 v = *(const float4*)&src[(size_t)off * 4];
    short4v s;
    s[0] = (short)f2b(v.x); s[1] = (short)f2b(v.y);
    s[2] = (short)f2b(v.z); s[3] = (short)f2b(v.w);
    *(short4v*)&dst[(size_t)i * 4] = s;
  }
}

// C[8192 x N] = A[8192 x 1024](bf16) * W^T (W [N x 1024] bf16 row-major).
// 256x128 tile, BK=64, 512 thr (8 waves 4Mx2N), 3 LDS buffers, prefetch
// distance 2, counted vmcnt(6) (never drains in steady state), raw barriers.
// QKV=true: N=3072, RoPE fused into epilogue (Q scaled by 0.125*log2e).
template <bool QKV>
__global__ __launch_bounds__(512, 2) void gemm256(
    const unsigned short* __restrict__ A,
    const unsigned short* __restrict__ W,
    void* __restrict__ Cv,
    const float* __restrict__ cosb, const float* __restrict__ sinb) {
  // 3 x (A 256x64 + B 128x64) shorts = 73728 shorts = 144 KiB
  __shared__ __align__(16) unsigned short lds[73728];
  const int tid = threadIdx.x, wave = tid >> 6, lane = tid & 63;
  const int bm = blockIdx.x << 8, bnc = blockIdx.y << 7;
  const int wr = (wave >> 1) << 6, wc = (wave & 1) << 6;
  const int lr = lane & 15, hi4 = lane >> 4;
  // staging geometry: slot s = inst*512+tid -> row = inst*64 + (tid>>3),
  // col-group (pre-swizzled source) = (tid&7) ^ (row&7); row&7 == rowb&7.
  const int rowb = tid >> 3;
  const int cgA = (tid & 7) ^ (rowb & 7);
  const unsigned short* aSrc = A + (size_t)(bm + rowb) * 1024 + (cgA << 3);
  const unsigned short* bSrc = W + (size_t)(bnc + rowb) * 1024 + (cgA << 3);

  f32x4 acc[4][4] = {};

#define STAGE(t, bi)                                                           \
  do {                                                                         \
    unsigned short* As_ = lds + (bi) * 24576;                                  \
    unsigned short* Bs_ = As_ + 16384;                                         \
    const int k0_ = (t) << 6;                                                  \
    _Pragma("unroll") for (int i = 0; i < 4; ++i)                              \
        GLD16(aSrc + (size_t)(i << 6) * 1024 + k0_,                            \
              As_ + (((i << 9) + tid) << 3));                                  \
    _Pragma("unroll") for (int j = 0; j < 2; ++j)                              \
        GLD16(bSrc + (size_t)(j << 6) * 1024 + k0_,                            \
              Bs_ + (((j << 9) + tid) << 3));                                  \
  } while (0)

  STAGE(0, 0);
  STAGE(1, 1);
  asm volatile("s_waitcnt vmcnt(6)" ::: "memory");  // tile 0 landed
  __builtin_amdgcn_s_barrier();
  __builtin_amdgcn_sched_barrier(0);

  int bi = 0;
#pragma unroll
  for (int t = 0; t < 16; ++t) {
    int pf = bi + 2; if (pf >= 3) pf -= 3;
    if (t < 14) STAGE(t + 2, pf);  // issue early; lands after consumers done
    const unsigned short* As = lds + bi * 24576;
    const unsigned short* Bs = As + 16384;
    short8 af[2][4], bfr[2][4];
#pragma unroll
    for (int kk = 0; kk < 2; ++kk)
#pragma unroll
      for (int x = 0; x < 4; ++x) {
        int ra = wr + x * 16 + lr;
        af[kk][x] = *(const short8*)&As[ra * 64 + (((hi4 + kk * 4) ^ (ra & 7)) << 3)];
        int rb = wc + x * 16 + lr;
        bfr[kk][x] = *(const short8*)&Bs[rb * 64 + (((hi4 + kk * 4) ^ (rb & 7)) << 3)];
      }
    __builtin_amdgcn_s_setprio(1);
#pragma unroll
    for (int kk = 0; kk < 2; ++kk)
#pragma unroll
      for (int mm = 0; mm < 4; ++mm)
#pragma unroll
        for (int nn = 0; nn < 4; ++nn)
          acc[mm][nn] = MFMA(af[kk][mm], bfr[kk][nn], acc[mm][nn]);
    __builtin_amdgcn_s_setprio(0);
    __builtin_amdgcn_sched_barrier(0);
    if (t < 14) asm volatile("s_waitcnt vmcnt(6)" ::: "memory");  // t+1 landed
    else        asm volatile("s_waitcnt vmcnt(0)" ::: "memory");
    __builtin_amdgcn_s_barrier();
    __builtin_amdgcn_sched_barrier(0);
    if (++bi == 3) bi = 0;
  }
#undef STAGE

  const int rg = hi4 << 2;
  if constexpr (QKV) {
    const int grp = bnc >> 10;  // 0=Q 1=K 2=V
    unsigned short* Cbuf = (unsigned short*)Cv + (size_t)grp * 8388608;
    const int colbase = (bnc & 1023) + wc;
    if (grp < 2) {
      // reuse LDS (free now) for cos/sin [256][32] fp32, staged via gld_lds
      float* csf = (float*)lds;
      float* snf = csf + 8192;
#pragma unroll
      for (int i = 0; i < 4; ++i) {
        int s = (i << 9) + tid;
        int row = s >> 3, c4 = (s & 7) << 2;
        GLD16(cosb + (size_t)(bm + row) * 64 + c4, csf + s * 4);
        GLD16(sinb + (size_t)(bm + row) * 64 + c4, snf + s * 4);
      }
      asm volatile("s_waitcnt vmcnt(0)" ::: "memory");
      __builtin_amdgcn_s_barrier();
      __builtin_amdgcn_sched_barrier(0);
      // Q gets 0.125 * log2(e) so attention softmax runs in exp2 domain.
      const float sc = (grp == 0) ? 0.18033688011112042f : 1.0f;
#pragma unroll
      for (int mm = 0; mm < 4; ++mm)
#pragma unroll
        for (int r = 0; r < 4; ++r) {
          int rloc = wr + mm * 16 + rg + r;
          size_t rowoff = (size_t)(bm + rloc) * 1024;
#pragma unroll
          for (int nn = 0; nn < 2; ++nn) {
            int d = nn * 16 + lr;
            float c = csf[rloc * 32 + d], s2 = snf[rloc * 32 + d];
            float lo = acc[mm][nn][r], hi = acc[mm][nn + 2][r];
            Cbuf[rowoff + colbase + nn * 16 + lr]      = f2b((lo * c - hi * s2) * sc);
            Cbuf[rowoff + colbase + nn * 16 + lr + 32] = f2b((hi * c + lo * s2) * sc);
          }
        }
    } else {
#pragma unroll
      for (int mm = 0; mm < 4; ++mm)
#pragma unroll
        for (int nn = 0; nn < 4; ++nn)
#pragma unroll
          for (int r = 0; r < 4; ++r)
            Cbuf[(size_t)(bm + wr + mm * 16 + rg + r) * 1024 + colbase + nn * 16 + lr] =
                f2b(acc[mm][nn][r]);
    }
  } else {
    float* C = (float*)Cv;
#pragma unroll
    for (int mm = 0; mm < 4; ++mm)
#pragma unroll
      for (int nn = 0; nn < 4; ++nn)
#pragma unroll
        for (int r = 0; r < 4; ++r)
          C[(size_t)(bm + wr + mm * 16 + rg + r) * 1024 + bnc + wc + nn * 16 + lr] =
              acc[mm][nn][r];
  }
}

// Causal flash attention v3 (unchanged from round 6). 1D grid 1024, LPT
// heavy-first, 4 waves x 32 q-rows, dbuf K/V, d-major V, defer-max, exp2.
__global__ __launch_bounds__(256, 2) void attn_kernel(
    const unsigned short* __restrict__ Q,
    const unsigned short* __restrict__ K,
    const unsigned short* __restrict__ V,
    unsigned short* __restrict__ O) {
  __shared__ unsigned short Ks[2][64][72];
  __shared__ unsigned short Vt[2][64][72];
  __shared__ unsigned short Ps[4][16][72];
  const int tid = threadIdx.x, wave = tid >> 6, lane = tid & 63;
  const int idx = blockIdx.x;
  const int bh = idx & 127;
  const int b = bh >> 4, h = bh & 15;
  const int qb = 7 - (idx >> 7);
  const int tok0 = b << 10;
  const int lr = lane & 15, hi4 = lane >> 4, lk8 = hi4 << 3;
  const int rg = hi4 << 2;
  const int qrow0 = (qb << 7) + (wave << 5);

  short8 qf[2][2];
#pragma unroll
  for (int mt = 0; mt < 2; ++mt) {
    const unsigned short* qp = &Q[(size_t)(tok0 + qrow0 + mt * 16 + lr) * 1024 + h * 64];
#pragma unroll
    for (int kk = 0; kk < 2; ++kk) qf[mt][kk] = *(const short8*)&qp[kk * 32 + lk8];
  }

  f32x4 acc[2][4] = {};
  float m[2][4], l[2][4];
#pragma unroll
  for (int mt = 0; mt < 2; ++mt)
#pragma unroll
    for (int r = 0; r < 4; ++r) { m[mt][r] = -1e30f; l[mt][r] = 0.f; }

  const int krow = tid >> 3, kcol = (tid & 7) << 3;
  const int vd = tid & 63, vko0 = tid >> 6;
  short8 kst[2], vst[2];

#define LOADT(kbx)                                                                 \
  do {                                                                             \
    const int kr0_ = tok0 + ((kbx) << 6);                                          \
    _Pragma("unroll") for (int it = 0; it < 2; ++it)                               \
        kst[it] = *(const short8*)&K[(size_t)(kr0_ + krow + it * 32) * 1024 +      \
                                     h * 64 + kcol];                               \
    _Pragma("unroll") for (int it = 0; it < 2; ++it) {                             \
      const unsigned short* vp_ =                                                  \
          &V[(size_t)(kr0_ + ((vko0 + it * 4) << 3)) * 1024 + h * 64 + vd];        \
      _Pragma("unroll") for (int i = 0; i < 8; ++i)                                \
          vst[it][i] = (short)vp_[(size_t)i * 1024];                               \
    }                                                                              \
  } while (0)

#define STORET(bi)                                                                 \
  do {                                                                             \
    _Pragma("unroll") for (int it = 0; it < 2; ++it)                               \
        *(short8*)&Ks[bi][krow + it * 32][kcol] = kst[it];                         \
    _Pragma("unroll") for (int it = 0; it < 2; ++it)                               \
        *(short8*)&Vt[bi][vd][(vko0 + it * 4) << 3] = vst[it];                     \
  } while (0)

  const int nkb = (qb + 1) << 1;
  LOADT(0);
  STORET(0);
  __syncthreads();

  for (int kb = 0; kb < nkb; ++kb) {
    const int cur = kb & 1;
    const bool more = (kb + 1 < nkb);
    if (more) LOADT(kb + 1);

    float sc[2][4][4];
#pragma unroll
    for (int ct = 0; ct < 4; ++ct) {
      short8 kf0 = *(const short8*)&Ks[cur][ct * 16 + lr][lk8];
      short8 kf1 = *(const short8*)&Ks[cur][ct * 16 + lr][32 + lk8];
#pragma unroll
      for (int mt = 0; mt < 2; ++mt) {
        f32x4 s = {};
        s = MFMA(qf[mt][0], kf0, s);
        s = MFMA(qf[mt][1], kf1, s);
#pragma unroll
        for (int r = 0; r < 4; ++r) sc[mt][ct][r] = s[r];
      }
    }
    if (kb >= 2 * qb) {
#pragma unroll
      for (int mt = 0; mt < 2; ++mt)
#pragma unroll
        for (int ct = 0; ct < 4; ++ct)
#pragma unroll
          for (int r = 0; r < 4; ++r) {
            int kg = (kb << 6) + ct * 16 + lr;
            int qg = qrow0 + mt * 16 + rg + r;
            if (kg > qg) sc[mt][ct][r] = -1e30f;
          }
    }

#pragma unroll
    for (int mt = 0; mt < 2; ++mt) {
      float mx[4];
#pragma unroll
      for (int r = 0; r < 4; ++r)
        mx[r] = fmaxf(fmaxf(sc[mt][0][r], sc[mt][1][r]),
                      fmaxf(sc[mt][2][r], sc[mt][3][r]));
#pragma unroll
      for (int off = 1; off < 16; off <<= 1)
#pragma unroll
        for (int r = 0; r < 4; ++r) mx[r] = fmaxf(mx[r], __shfl_xor(mx[r], off));
      bool need = (mx[0] > m[mt][0] + 8.f) | (mx[1] > m[mt][1] + 8.f) |
                  (mx[2] > m[mt][2] + 8.f) | (mx[3] > m[mt][3] + 8.f);
      if (__any(need)) {
#pragma unroll
        for (int r = 0; r < 4; ++r) {
          float mn = fmaxf(m[mt][r], mx[r]);
          float alpha = __builtin_amdgcn_exp2f(m[mt][r] - mn);
          m[mt][r] = mn;
          l[mt][r] *= alpha;
#pragma unroll
          for (int dt = 0; dt < 4; ++dt) acc[mt][dt][r] *= alpha;
        }
      }
      float rs[4] = {0.f, 0.f, 0.f, 0.f};
      float p[4][4];
#pragma unroll
      for (int ct = 0; ct < 4; ++ct)
#pragma unroll
        for (int r = 0; r < 4; ++r) {
          p[ct][r] = __builtin_amdgcn_exp2f(sc[mt][ct][r] - m[mt][r]);
          rs[r] += p[ct][r];
        }
#pragma unroll
      for (int off = 1; off < 16; off <<= 1)
#pragma unroll
        for (int r = 0; r < 4; ++r) rs[r] += __shfl_xor(rs[r], off);
#pragma unroll
      for (int r = 0; r < 4; ++r) l[mt][r] += rs[r];
#pragma unroll
      for (int ct = 0; ct < 4; ++ct)
#pragma unroll
        for (int r = 0; r < 4; ++r)
          Ps[wave][rg + r][ct * 16 + lr] = f2b(p[ct][r]);
      asm volatile("s_waitcnt lgkmcnt(0)" ::: "memory");
      __builtin_amdgcn_sched_barrier(0);
#pragma unroll
      for (int kk = 0; kk < 2; ++kk) {
        short8 pf = *(const short8*)&Ps[wave][lr][kk * 32 + lk8];
#pragma unroll
        for (int dt = 0; dt < 4; ++dt) {
          short8 vf = *(const short8*)&Vt[cur][dt * 16 + lr][kk * 32 + lk8];
          acc[mt][dt] = MFMA(pf, vf, acc[mt][dt]);
        }
      }
    }

    if (more) {
      STORET(cur ^ 1);
      __syncthreads();
    }
  }
#undef LOADT
#undef STORET

#pragma unroll
  for (int mt = 0; mt < 2; ++mt) {
    float inv[4];
#pragma unroll
    for (int r = 0; r < 4; ++r) inv[r] = 1.0f / l[mt][r];
#pragma unroll
    for (int dt = 0; dt < 4; ++dt)
#pragma unroll
      for (int r = 0; r < 4; ++r) {
        int trow = tok0 + qrow0 + mt * 16 + rg + r;
        O[(size_t)trow * 1024 + h * 64 + dt * 16 + lr] = f2b(acc[mt][dt][r] * inv[r]);
      }
  }
}

extern "C" void kernel_launch(void* const* d_in, const int* in_sizes, int n_in,
                              void* d_out, int out_size, void* d_ws, size_t ws_size,
                              hipStream_t stream) {
  const float* hidden = (const float*)d_in[0];
  const float* q_w    = (const float*)d_in[1];
  const float* k_w    = (const float*)d_in[2];
  const float* v_w    = (const float*)d_in[3];
  const float* o_w    = (const float*)d_in[4];
  const float* cosb   = (const float*)d_in[5];
  const float* sinb   = (const float*)d_in[6];

  const size_t TD = (size_t)8192 * 1024;
  unsigned short* ws  = (unsigned short*)d_ws;
  unsigned short* Qb  = ws;
  unsigned short* Kb  = ws + TD;
  unsigned short* Vb  = ws + 2 * TD;
  unsigned short* hBF = ws + 3 * TD;        // hidden bf16; aliased as AO after QKV
  unsigned short* wBF = ws + 4 * TD;        // q,k,v,o weights bf16 (4 x 1M)

  convert_kernel<<<4096, 256, 0, stream>>>(hidden, q_w, k_w, v_w, o_w, hBF);
  gemm256<true><<<dim3(32, 24), 512, 0, stream>>>(hBF, wBF, Qb, cosb, sinb);
  attn_kernel<<<1024, 256, 0, stream>>>(Qb, Kb, Vb, hBF /*AO*/);
  gemm256<false><<<dim3(32, 8), 512, 0, stream>>>(
      hBF, wBF + 3 * 1048576, d_out, nullptr, nullptr);
}